// Round 1
// baseline (144.108 us; speedup 1.0000x reference)
//
#include <hip/hip_runtime.h>
#include <hip/hip_bf16.h>
#include <stdint.h>

#define HEAD 64
#define CEMB 1024
#define BB 8
#define TSEQ 2048

typedef __attribute__((ext_vector_type(8))) short bf16x8;
typedef __attribute__((ext_vector_type(4))) float f32x4;

__device__ __forceinline__ unsigned short f2bf(float f) {
    union { float f; uint32_t u; } c; c.f = f;
    uint32_t u = c.u + 0x7FFF + ((c.u >> 16) & 1);
    return (unsigned short)(u >> 16);
}
__device__ __forceinline__ ushort4 f4bf(float4 v) {
    ushort4 u; u.x = f2bf(v.x); u.y = f2bf(v.y); u.z = f2bf(v.z); u.w = f2bf(v.w);
    return u;
}

// ---------------- Kernel 0: W -> WTf, MFMA-fragment order (unchanged) --------
// Fragment (kc, j): 64 lanes x 16B contiguous (1 KB); n = j*16+(lane&15),
// k = kc*32 + (lane>>4)*8 + e.  j: 0-3 K, 4-7 Q(scaled), 8-11 V.
__global__ __launch_bounds__(256) void prep_w(
        const float* __restrict__ Wk, const float* __restrict__ bk,
        const float* __restrict__ Wq, const float* __restrict__ bq,
        const float* __restrict__ Wv, const float* __restrict__ bv,
        unsigned short* __restrict__ WTf, float* __restrict__ biasb) {
    __shared__ float Wl[3][32][64];
    const int kc = blockIdx.x;               // 0..31
    const int tid = threadIdx.x;
    const float* Ws[3] = {Wk, Wq, Wv};
    const int row = tid >> 3, cf = (tid & 7) * 8;
    #pragma unroll
    for (int p = 0; p < 3; p++) {
        const float* W = Ws[p] + (long)(kc * 32 + row) * 64 + cf;
        float4 v0 = *(const float4*)(W);
        float4 v1 = *(const float4*)(W + 4);
        *(float4*)(&Wl[p][row][cf]) = v0;
        *(float4*)(&Wl[p][row][cf + 4]) = v1;
    }
    __syncthreads();
    #pragma unroll
    for (int i = 0; i < 3; i++) {
        int cid = i * 256 + tid;             // 0..767 = j*64 + lane
        int lane = cid & 63;
        int l15 = lane & 15, q4 = lane >> 4;
        int n = (cid >> 6) * 16 + l15;
        int p = n >> 6, col = n & 63;
        float scale = (p == 1) ? 0.03125f : 1.0f;
        unsigned short o[8];
        for (int e = 0; e < 8; e++) o[e] = f2bf(Wl[p][q4 * 8 + e][col] * scale);
        *(int4*)(WTf + (long)kc * 6144 + (long)cid * 8) = *(int4*)o;
    }
    if (kc == 0 && tid < 192) {
        const float* bs[3] = {bk, bq, bv};
        int p = tid >> 6;
        biasb[tid] = bs[p][tid & 63] * ((p == 1) ? 0.03125f : 1.0f);
    }
}

// ---------------- Kernel 1: projections, register-resident B (half-K) --------
// grid 256 x 768thr (12 waves, 1 block/CU). Wave j owns n-tile j. B-stripe
// held HALF-K at a time: Breg[16] = 64 VGPRs (reloaded once, L2-hot) so the
// wave fits the 168-VGPR cap at 3 waves/EU -- R5's Breg[32] spilled (VGPR=84).
__global__ __launch_bounds__(768) void proj_gemm(
        const float* __restrict__ x, const unsigned short* __restrict__ WTf,
        const float* __restrict__ biasb,
        unsigned short* __restrict__ Kb, unsigned short* __restrict__ Qb,
        unsigned short* __restrict__ VTb) {
    __shared__ __align__(16) unsigned short As[64 * 1032];   // 132 KB

    const int tid = threadIdx.x;
    const int lane = tid & 63, w = tid >> 6;     // w = n-tile 0..11
    const int l15 = lane & 15, q4 = lane >> 4;
    const long rowbase = (long)blockIdx.x * 64;
    const float* xg = x + rowbase * CEMB;
    const unsigned short* Bg = WTf + w * 512 + (long)lane * 8;

    f32x4 z = {0.f, 0.f, 0.f, 0.f};
    f32x4 acc[4];
    #pragma unroll
    for (int m = 0; m < 4; m++) acc[m] = z;

    bf16x8 Breg[16];

    // ---- stage segment 0 (rows x k[0:128]) ----
    {
        #pragma unroll
        for (int it = 0; it < 3; it++) {
            int i = it * 768 + tid;
            if (i < 2048) {
                int row = i >> 5, c4 = (i & 31) * 4;
                float4 v = *(const float4*)(xg + row * CEMB + c4);
                *(ushort4*)(As + row * 1032 + c4) = f4bf(v);
            }
        }
    }
    __syncthreads();

    // ---- pipelined K-loop: 2 halves x 4 segments ----
    #pragma unroll
    for (int half = 0; half < 2; half++) {
        // load this half's 16 B-fragments (64 VGPRs; L2-hot 1KB coalesced)
        #pragma unroll
        for (int i = 0; i < 16; i++)
            Breg[i] = *(const bf16x8*)(Bg + (long)(half * 16 + i) * 6144);

        #pragma unroll
        for (int ss = 0; ss < 4; ss++) {
            const int s = half * 4 + ss;
            float4 pf[3];
            // issue seg s+1 global loads (in flight across MFMA below)
            if (s < 7) {
                #pragma unroll
                for (int it = 0; it < 3; it++) {
                    int i = it * 768 + tid;
                    if (i < 2048) {
                        int row = i >> 5, c4 = (i & 31) * 4;
                        pf[it] = *(const float4*)(xg + row * CEMB + (s + 1) * 128 + c4);
                    }
                }
            }
            // compute seg s: 4 kc x 4 m-tiles, B from registers
            #pragma unroll
            for (int kc = 0; kc < 4; kc++) {
                const int kg = s * 4 + kc;
                #pragma unroll
                for (int m = 0; m < 4; m++) {
                    bf16x8 a = *(const bf16x8*)(As + (m * 16 + l15) * 1032 + kg * 32 + q4 * 8);
                    acc[m] = __builtin_amdgcn_mfma_f32_16x16x32_bf16(a, Breg[ss * 4 + kc], acc[m], 0, 0, 0);
                }
            }
            // store seg s+1 (disjoint LDS region), then barrier
            if (s < 7) {
                #pragma unroll
                for (int it = 0; it < 3; it++) {
                    int i = it * 768 + tid;
                    if (i < 2048) {
                        int row = i >> 5, c4 = (i & 31) * 4;
                        *(ushort4*)(As + row * 1032 + (s + 1) * 128 + c4) = f4bf(pf[it]);
                    }
                }
                __syncthreads();
            }
        }
    }

    // ---- epilogue: +bias, cast bf16, per-wave scatter ----
    const int n = w * 16 + l15;
    const float bias = biasb[n];
    #pragma unroll
    for (int m = 0; m < 4; m++) {
        const long row0 = rowbase + m * 16 + q4 * 4;
        if (n < 128) {
            unsigned short* dst = (n < 64) ? (Kb + row0 * HEAD + n)
                                           : (Qb + row0 * HEAD + (n - 64));
            for (int r = 0; r < 4; r++)
                dst[r * HEAD] = f2bf(acc[m][r] + bias);
        } else {
            const int h = n - 128;
            const long b = row0 >> 11; const int t = (int)(row0 & 2047);
            ushort4 pk;
            pk.x = f2bf(acc[m][0] + bias);
            pk.y = f2bf(acc[m][1] + bias);
            pk.z = f2bf(acc[m][2] + bias);
            pk.w = f2bf(acc[m][3] + bias);
            *(ushort4*)(VTb + b * (HEAD * (long)TSEQ) + (long)h * TSEQ + t) = pk;
        }
    }
}

// ---------------- Kernel 2: causal softplus-attention, 8 waves ---------------
// grid 512 x 512thr. 8 waves split s-chunks; P-scratch and tree-reduction
// regions share one 37 KB LDS union -> 2 blocks/CU, 16 waves/CU.
// R0 change: complementary-pair bid->tile remap. Round-robin dispatch puts
// bids c and c+256 on the same CU; map them to tiles ti and 63-ti (same
// batch, same XCD) so every CU carries a uniform 65 chunk-units instead of
// the previous {13..6}-wave-iter spread (1.45x tail).
__global__ __launch_bounds__(512) void attn(
        const unsigned short* __restrict__ Kb, const unsigned short* __restrict__ Qb,
        const unsigned short* __restrict__ VTb, float* __restrict__ out) {
    __shared__ __align__(16) char sm[36864];   // max(Pl 20480, red 36864)
    unsigned short* Pl = (unsigned short*)sm;  // [8 waves][32*40]
    float* red = (float*)sm;                   // [4][64*36]

    const int tid = threadIdx.x;
    const int lane = tid & 63, w = tid >> 6;   // 8 waves
    const int l15 = lane & 15, q4 = lane >> 4;

    const int bid = blockIdx.x;
    const int half = bid >> 8;                 // 0: bids 0..255, 1: 256..511
    const int slot = (bid & 255) >> 3;         // 0..31
    const int ti = half ? slot : 63 - slot;    // CU pair (c, c+256) -> ti, 63-ti
    const int b = bid & 7;
    const int t0 = ti * 32;

    const unsigned short* kb  = Kb  + (long)b * TSEQ * HEAD;
    const unsigned short* qb  = Qb  + (long)b * TSEQ * HEAD;
    const unsigned short* vtb = VTb + (long)b * HEAD * TSEQ;

    bf16x8 kf[2][2];
    for (int tt = 0; tt < 2; tt++)
        for (int kk = 0; kk < 2; kk++)
            kf[tt][kk] = *(const bf16x8*)(kb + (t0 + tt * 16 + l15) * HEAD + kk * 32 + q4 * 8);

    f32x4 z = {0.f, 0.f, 0.f, 0.f};
    f32x4 oacc[4][2];
    for (int hh = 0; hh < 4; hh++) for (int tt = 0; tt < 2; tt++) oacc[hh][tt] = z;

    bf16x8 qpf[2][2], vpf[4];
    if (w <= ti) {
        const int s0 = w * 32;
        for (int st2 = 0; st2 < 2; st2++)
            for (int kk = 0; kk < 2; kk++)
                qpf[st2][kk] = *(const bf16x8*)(qb + (s0 + st2 * 16 + l15) * HEAD + kk * 32 + q4 * 8);
        for (int hh = 0; hh < 4; hh++)
            vpf[hh] = *(const bf16x8*)(vtb + (hh * 16 + l15) * (long)TSEQ + s0 + q4 * 8);
    }

    unsigned short* myP = Pl + w * 1280;
    for (int c = w; c <= ti; c += 8) {
        const int s0 = c * 32;

        bf16x8 qf[2][2], vf[4];
        for (int st2 = 0; st2 < 2; st2++)
            for (int kk = 0; kk < 2; kk++) qf[st2][kk] = qpf[st2][kk];
        for (int hh = 0; hh < 4; hh++) vf[hh] = vpf[hh];

        if (c + 8 <= ti) {
            const int sn = (c + 8) * 32;
            for (int st2 = 0; st2 < 2; st2++)
                for (int kk = 0; kk < 2; kk++)
                    qpf[st2][kk] = *(const bf16x8*)(qb + (sn + st2 * 16 + l15) * HEAD + kk * 32 + q4 * 8);
            for (int hh = 0; hh < 4; hh++)
                vpf[hh] = *(const bf16x8*)(vtb + (hh * 16 + l15) * (long)TSEQ + sn + q4 * 8);
        }

        // S^T = Q K^T: 2 s-tiles x 2 t-tiles
        f32x4 sc[2][2];
        for (int st2 = 0; st2 < 2; st2++)
            for (int tt = 0; tt < 2; tt++) {
                f32x4 s = z;
                s = __builtin_amdgcn_mfma_f32_16x16x32_bf16(qf[st2][0], kf[tt][0], s, 0, 0, 0);
                s = __builtin_amdgcn_mfma_f32_16x16x32_bf16(qf[st2][1], kf[tt][1], s, 0, 0, 0);
                sc[st2][tt] = s;
            }
        // softplus + causal mask; pack bf16 -> P^T LDS [t-local][s-local]
        for (int tt = 0; tt < 2; tt++) {
            const int tg = t0 + tt * 16 + l15;
            for (int st2 = 0; st2 < 2; st2++) {
                ushort4 pk;
                unsigned short pv[4];
                for (int r = 0; r < 4; r++) {
                    int sg = s0 + st2 * 16 + q4 * 4 + r;
                    float p = __logf(1.0f + __expf(sc[st2][tt][r]));
                    if (sg > tg) p = 0.0f;
                    pv[r] = f2bf(p);
                }
                pk.x = pv[0]; pk.y = pv[1]; pk.z = pv[2]; pk.w = pv[3];
                *(ushort4*)(myP + (tt * 16 + l15) * 40 + st2 * 16 + q4 * 4) = pk;
            }
        }
        __threadfence_block();
        bf16x8 pf0 = *(const bf16x8*)(myP + l15 * 40 + q4 * 8);
        bf16x8 pf1 = *(const bf16x8*)(myP + (16 + l15) * 40 + q4 * 8);
        for (int hh = 0; hh < 4; hh++) {
            oacc[hh][0] = __builtin_amdgcn_mfma_f32_16x16x32_bf16(vf[hh], pf0, oacc[hh][0], 0, 0, 0);
            oacc[hh][1] = __builtin_amdgcn_mfma_f32_16x16x32_bf16(vf[hh], pf1, oacc[hh][1], 0, 0, 0);
        }
    }

    // ---- 3-stage tree reduction over 8 waves (red unions Pl; synced) ----
    __syncthreads();                           // all Pl use done
    if (w >= 4) {
        float* r0 = red + (w - 4) * 2304 + lane * 36;
        for (int hh = 0; hh < 4; hh++)
            for (int tt = 0; tt < 2; tt++)
                *(f32x4*)(r0 + (hh * 2 + tt) * 4) = oacc[hh][tt];
    }
    __syncthreads();
    if (w < 4) {
        const float* r0 = red + w * 2304 + lane * 36;
        for (int hh = 0; hh < 4; hh++)
            for (int tt = 0; tt < 2; tt++)
                oacc[hh][tt] += *(const f32x4*)(r0 + (hh * 2 + tt) * 4);
    }
    __syncthreads();
    if (w == 2 || w == 3) {
        float* r0 = red + (w - 2) * 2304 + lane * 36;
        for (int hh = 0; hh < 4; hh++)
            for (int tt = 0; tt < 2; tt++)
                *(f32x4*)(r0 + (hh * 2 + tt) * 4) = oacc[hh][tt];
    }
    __syncthreads();
    if (w < 2) {
        const float* r0 = red + w * 2304 + lane * 36;
        for (int hh = 0; hh < 4; hh++)
            for (int tt = 0; tt < 2; tt++)
                oacc[hh][tt] += *(const f32x4*)(r0 + (hh * 2 + tt) * 4);
    }
    __syncthreads();
    if (w == 1) {
        float* r0 = red + lane * 36;
        for (int hh = 0; hh < 4; hh++)
            for (int tt = 0; tt < 2; tt++)
                *(f32x4*)(r0 + (hh * 2 + tt) * 4) = oacc[hh][tt];
    }
    __syncthreads();
    if (w == 0) {
        const float* r0 = red + lane * 36;
        for (int hh = 0; hh < 4; hh++)
            for (int tt = 0; tt < 2; tt++)
                oacc[hh][tt] += *(const f32x4*)(r0 + (hh * 2 + tt) * 4);
        for (int tt = 0; tt < 2; tt++) {
            float* ob = out + ((long)b * TSEQ + t0 + tt * 16 + l15) * HEAD + q4 * 4;
            for (int hh = 0; hh < 4; hh++)
                *(f32x4*)(ob + hh * 16) = oacc[hh][tt];
        }
    }
}

// ---------------- host launch ------------------------------------------------
extern "C" void kernel_launch(void* const* d_in, const int* in_sizes, int n_in,
                              void* d_out, int out_size, void* d_ws, size_t ws_size,
                              hipStream_t stream) {
    const float* x  = (const float*)d_in[0];
    const float* Wk = (const float*)d_in[1];
    const float* bk = (const float*)d_in[2];
    const float* Wq = (const float*)d_in[3];
    const float* bq = (const float*)d_in[4];
    const float* Wv = (const float*)d_in[5];
    const float* bv = (const float*)d_in[6];
    float* out = (float*)d_out;

    char* ws = (char*)d_ws;
    unsigned short* WTf   = (unsigned short*)(ws);                      // 384 KB
    float*          biasb = (float*)(ws + 393216);                      // 768 B
    unsigned short* Kb    = (unsigned short*)(ws + 524288);             // 2 MB
    unsigned short* Qb    = (unsigned short*)(ws + 524288 + 2097152);   // 2 MB
    unsigned short* VTb   = (unsigned short*)(ws + 524288 + 4194304);   // 2 MB

    prep_w<<<32, 256, 0, stream>>>(Wk, bk, Wq, bq, Wv, bv, WTf, biasb);
    proj_gemm<<<256, 768, 0, stream>>>(x, WTf, biasb, Kb, Qb, VTb);
    attn<<<512, 512, 0, stream>>>(Kb, Qb, VTb, out);
}